// Round 8
// baseline (447.051 us; speedup 1.0000x reference)
//
#include <hip/hip_runtime.h>

#define B_    4
#define HIMG  256
#define WIMG  256
#define C_    128
#define NH_   4
#define WS8   8
#define L_    64
#define NWX   32
#define NPATCH (HIMG*WIMG)           // 65536
#define TTOT  (NPATCH + 200)         // 65736
#define SCALE 0.17677669529663689f   // 32^-0.5

typedef __bf16 bf16x8 __attribute__((ext_vector_type(8)));
typedef __bf16 bf16x4 __attribute__((ext_vector_type(4)));
typedef float  f32x4  __attribute__((ext_vector_type(4)));

// ---- shared memory: two windows per 512-thread block ----
// per-window region (offset win*WIN_BYTES):
//   per-wave scratch @ w*13568: [64][72] bf16 Q(cols 0..31)|K(cols 32..63), P overlays
//                               [32][68] bf16 V^T @ +9216
//   px exchange [64][136] bf16 overlays offset 0 after barrier (17408 B)
//   mask [64][68] f32 @ +54272 (17408 B) — staged once, read by softmax
#define MASK_OFF   54272
#define WIN_BYTES  71680             // 54272 + 64*68*4
#define SMEM_BYTES (2*WIN_BYTES)     // 143360 -> 1 block/CU, 8 waves co-resident
#define QK_STRIDE  72
#define KOFF       32
#define VT_OFF     9216
#define VT_STRIDE  68
#define WV_BYTES   13568
#define PX_STRIDE  136
#define MSK_STRIDE 68                // f32
// token-block reuse of window-0 region (47600 B used):
#define TOK_XS_OFF 0
#define TOK_QS_OFF 27200
#define TOK_KS_OFF 34000
#define TOK_VS_OFF 40800
#define TOK_STR    34

// ---- workspace layout (bytes) ----
#define WS_WQ     0          // 384*128 bf16 = 98304
#define WS_WP     98304      // 128*128 bf16 = 32768
#define WS_BIASP  131072     // 4*64*16*4 f32 = 65536  (biasP[h][row][lo][nt])
#define WS_QKVTOK 196608     // 8 * 38400 f32 = 1228800

// ---------------------------------------------------------------- prep
__global__ __launch_bounds__(256)
void prep_kernel(const float* __restrict__ Wq, const float* __restrict__ Wp,
                 const float* __restrict__ rel_table, const int* __restrict__ rel_index,
                 unsigned short* __restrict__ wq_b, unsigned short* __restrict__ wp_b,
                 float* __restrict__ biasP) {
    int id = blockIdx.x * 256 + threadIdx.x;
    if (id < 49152) {
        __bf16 v = (__bf16)Wq[id];
        wq_b[id] = *(unsigned short*)&v;
    } else if (id < 65536) {
        int i = id - 49152;
        __bf16 v = (__bf16)Wp[i];
        wp_b[i] = *(unsigned short*)&v;
    } else if (id < 81920) {
        int t = id - 65536;
        int h = t >> 12, ij = t & 4095;
        int row = ij >> 6, col = ij & 63;
        // transposed: [h][row][lo][nt] so softmax reads one float4 per (row,lo)
        biasP[((h * 64 + row) * 16 + (col & 15)) * 4 + (col >> 4)] =
            rel_table[rel_index[ij] * 4 + h];
    }
}

// ---------------------------------------------------------------- fused kernel
// blocks 0..7: token path (b,set), dispatched first -> hidden under window work.
// blocks 8..2055: 2 windows each (8 waves forced co-resident, R5 mechanism).
__global__ __launch_bounds__(512, 2)
void win2_kernel(const float* __restrict__ x, const float* __restrict__ det,
                 const float* __restrict__ inter, const float* __restrict__ mask,
                 const unsigned short* __restrict__ wq_u, const float* __restrict__ bqkv,
                 const unsigned short* __restrict__ wp_u, const float* __restrict__ bproj,
                 const float* __restrict__ biasP, float* __restrict__ qkvT_ws,
                 float* __restrict__ out) {
    __shared__ __align__(16) char SMEM[SMEM_BYTES];
    const __bf16* wq = (const __bf16*)wq_u;
    const __bf16* wp = (const __bf16*)wp_u;
    const int tid = threadIdx.x;
    const int bx = blockIdx.x;
    const f32x4 zz = {0.f, 0.f, 0.f, 0.f};

    if (bx >= 8) {
        // ================= window path =================
        const int win = tid >> 8;            // 0..1: window-in-block
        const int w   = (tid >> 6) & 3;      // wave-in-window == head
        const int l   = tid & 63;
        const int lo  = l & 15;
        const int hi  = l >> 4;

        const int gw = (bx - 8) * 2 + win;   // 0..4095 exact
        const int b  = gw >> 10;
        const int wi = (gw >> 5) & 31;
        const int wj = gw & 31;

        char* WB = SMEM + win * WIN_BYTES;
        __bf16* SW   = (__bf16*)(WB + w * WV_BYTES);            // [64][72]: Q|K, later P
        __bf16* VTs  = (__bf16*)(WB + w * WV_BYTES + VT_OFF);   // [32][68]: V^T
        __bf16* PXU  = (__bf16*)WB;                             // [64][136]: px union
        float*  mlds = (float*)(WB + MASK_OFF);                 // [64][68] f32 mask

        // ---------------- stage this window's mask into LDS (coalesced f32x4)
        {
            const float* maskW = mask + (size_t)(wi * NWX + wj) * 4096;
            int t = tid & 255;               // thread-in-window
#pragma unroll
            for (int u = 0; u < 4; ++u) {
                int f = u * 256 + t;         // float4 index 0..1023
                f32x4 v = *(const f32x4*)(maskW + f * 4);
                *(f32x4*)&mlds[(f >> 4) * MSK_STRIDE + (f & 15) * 4] = v;
            }
        }
        __syncthreads();

        // ---------------- phase 1: QKV accumulators
        const float* xw = x + (((size_t)(b * HIMG) + wi * WS8) * WIMG + wj * WS8) * C_;
        const float* arow[4];
#pragma unroll
        for (int mt = 0; mt < 4; ++mt) {
            int t = mt * 16 + lo;
            arow[mt] = xw + ((size_t)(t >> 3) * WIMG + (t & 7)) * C_ + hi * 8;
        }
        int nbase[6];
        const __bf16* brow[6];
#pragma unroll
        for (int g = 0; g < 3; ++g) {
            nbase[2 * g]     = g * 128 + 32 * w;
            nbase[2 * g + 1] = g * 128 + 32 * w + 16;
        }
#pragma unroll
        for (int nt = 0; nt < 6; ++nt)
            brow[nt] = wq + (size_t)(nbase[nt] + lo) * C_ + hi * 8;

        f32x4 acc[4][6];
#pragma unroll
        for (int mt = 0; mt < 4; ++mt)
#pragma unroll
            for (int nt = 0; nt < 6; ++nt) acc[mt][nt] = zz;

#pragma unroll
        for (int ks = 0; ks < 4; ++ks) {
            bf16x8 a[4], bb[6];
#pragma unroll
            for (int mt = 0; mt < 4; ++mt) {
                const float* pa = arow[mt] + ks * 32;
                float4 v0 = *(const float4*)pa;
                float4 v1 = *(const float4*)(pa + 4);
                bf16x8 av;
                av[0] = (__bf16)v0.x; av[1] = (__bf16)v0.y; av[2] = (__bf16)v0.z; av[3] = (__bf16)v0.w;
                av[4] = (__bf16)v1.x; av[5] = (__bf16)v1.y; av[6] = (__bf16)v1.z; av[7] = (__bf16)v1.w;
                a[mt] = av;
            }
#pragma unroll
            for (int nt = 0; nt < 6; ++nt)
                bb[nt] = *(const bf16x8*)(brow[nt] + ks * 32);
#pragma unroll
            for (int mt = 0; mt < 4; ++mt)
#pragma unroll
                for (int nt = 0; nt < 6; ++nt)
                    acc[mt][nt] = __builtin_amdgcn_mfma_f32_16x16x32_bf16(a[mt], bb[nt], acc[mt][nt], 0, 0, 0);
        }

        // ---------------- scatter Q, K, V^T to LDS (write all, then read)
#pragma unroll
        for (int nt = 0; nt < 6; ++nt) {
            float bq = bqkv[nbase[nt] + lo];
            if (nt < 2) {
                int col = nt * 16 + lo;
#pragma unroll
                for (int mt = 0; mt < 4; ++mt)
#pragma unroll
                    for (int r = 0; r < 4; ++r)
                        SW[(mt * 16 + hi * 4 + r) * QK_STRIDE + col] = (__bf16)(acc[mt][nt][r] + bq);
            } else if (nt < 4) {
                int col = KOFF + (nt - 2) * 16 + lo;
#pragma unroll
                for (int mt = 0; mt < 4; ++mt)
#pragma unroll
                    for (int r = 0; r < 4; ++r)
                        SW[(mt * 16 + hi * 4 + r) * QK_STRIDE + col] = (__bf16)(acc[mt][nt][r] + bq);
            } else {
                int d = (nt - 4) * 16 + lo;
#pragma unroll
                for (int mt = 0; mt < 4; ++mt) {
                    bf16x4 vv;
#pragma unroll
                    for (int r = 0; r < 4; ++r) vv[r] = (__bf16)(acc[mt][nt][r] + bq);
                    *(bf16x4*)&VTs[d * VT_STRIDE + mt * 16 + hi * 4] = vv;
                }
            }
        }

        bf16x8 aq[4], bk[4];
#pragma unroll
        for (int mt = 0; mt < 4; ++mt)
            aq[mt] = *(const bf16x8*)&SW[(mt * 16 + lo) * QK_STRIDE + hi * 8];
#pragma unroll
        for (int nt = 0; nt < 4; ++nt)
            bk[nt] = *(const bf16x8*)&SW[(nt * 16 + lo) * QK_STRIDE + KOFF + hi * 8];

        // ---------------- QK^T
        f32x4 lg[4][4];
#pragma unroll
        for (int mt = 0; mt < 4; ++mt)
#pragma unroll
            for (int nt = 0; nt < 4; ++nt)
                lg[mt][nt] = __builtin_amdgcn_mfma_f32_16x16x32_bf16(aq[mt], bk[nt], zz, 0, 0, 0);

        // ---------------- softmax, P -> scratch
        // bias: one float4 per (mt,r) from transposed biasP; mask: LDS f32.
#pragma unroll
        for (int mt = 0; mt < 4; ++mt) {
#pragma unroll
            for (int r = 0; r < 4; ++r) {
                int row = mt * 16 + hi * 4 + r;
                f32x4 bv4 = *(const f32x4*)&biasP[((w * 64 + row) * 16 + lo) * 4];
                float v[4];
                float m = -1e30f;
#pragma unroll
                for (int nt = 0; nt < 4; ++nt) {
                    float t = lg[mt][nt][r] * SCALE + bv4[nt] + mlds[row * MSK_STRIDE + nt * 16 + lo];
                    v[nt] = t;
                    m = fmaxf(m, t);
                }
                m = fmaxf(m, __shfl_xor(m, 1));
                m = fmaxf(m, __shfl_xor(m, 2));
                m = fmaxf(m, __shfl_xor(m, 4));
                m = fmaxf(m, __shfl_xor(m, 8));
                float s = 0.f;
#pragma unroll
                for (int nt = 0; nt < 4; ++nt) { v[nt] = __expf(v[nt] - m); s += v[nt]; }
                s += __shfl_xor(s, 1);
                s += __shfl_xor(s, 2);
                s += __shfl_xor(s, 4);
                s += __shfl_xor(s, 8);
                float inv = 1.0f / s;
#pragma unroll
                for (int nt = 0; nt < 4; ++nt)
                    SW[row * QK_STRIDE + nt * 16 + lo] = (__bf16)(v[nt] * inv);
            }
        }

        // ---------------- PV
        f32x4 pv[4][2];
#pragma unroll
        for (int mt = 0; mt < 4; ++mt)
#pragma unroll
            for (int nt = 0; nt < 2; ++nt) pv[mt][nt] = zz;
#pragma unroll
        for (int ks = 0; ks < 2; ++ks) {
            bf16x8 ap[4], bv[2];
#pragma unroll
            for (int mt = 0; mt < 4; ++mt)
                ap[mt] = *(const bf16x8*)&SW[(mt * 16 + lo) * QK_STRIDE + ks * 32 + hi * 8];
#pragma unroll
            for (int nt = 0; nt < 2; ++nt) {
                bf16x4 b0 = *(const bf16x4*)&VTs[(nt * 16 + lo) * VT_STRIDE + ks * 32 + hi * 8];
                bf16x4 b1 = *(const bf16x4*)&VTs[(nt * 16 + lo) * VT_STRIDE + ks * 32 + hi * 8 + 4];
                bf16x8 bb;
#pragma unroll
                for (int u = 0; u < 4; ++u) { bb[u] = b0[u]; bb[u + 4] = b1[u]; }
                bv[nt] = bb;
            }
#pragma unroll
            for (int mt = 0; mt < 4; ++mt)
#pragma unroll
                for (int nt = 0; nt < 2; ++nt)
                    pv[mt][nt] = __builtin_amdgcn_mfma_f32_16x16x32_bf16(ap[mt], bv[nt], pv[mt][nt], 0, 0, 0);
        }

        // ---------------- px exchange through per-window scratch union
        __syncthreads();   // all waves done reading their scratch
#pragma unroll
        for (int mt = 0; mt < 4; ++mt)
#pragma unroll
            for (int nt = 0; nt < 2; ++nt)
#pragma unroll
                for (int r = 0; r < 4; ++r)
                    PXU[(mt * 16 + hi * 4 + r) * PX_STRIDE + 32 * w + nt * 16 + lo] = (__bf16)pv[mt][nt][r];
        __syncthreads();

        // ---------------- proj (wave w -> out cols [32w, 32w+32))
        f32x4 po[4][2];
#pragma unroll
        for (int mt = 0; mt < 4; ++mt)
#pragma unroll
            for (int nt = 0; nt < 2; ++nt) po[mt][nt] = zz;
        const __bf16* wprow[2];
#pragma unroll
        for (int nt = 0; nt < 2; ++nt)
            wprow[nt] = wp + (size_t)(32 * w + nt * 16 + lo) * C_ + hi * 8;
#pragma unroll
        for (int ks = 0; ks < 4; ++ks) {
            bf16x8 apx[4], bw[2];
#pragma unroll
            for (int mt = 0; mt < 4; ++mt)
                apx[mt] = *(const bf16x8*)&PXU[(mt * 16 + lo) * PX_STRIDE + ks * 32 + hi * 8];
#pragma unroll
            for (int nt = 0; nt < 2; ++nt)
                bw[nt] = *(const bf16x8*)(wprow[nt] + ks * 32);
#pragma unroll
            for (int mt = 0; mt < 4; ++mt)
#pragma unroll
                for (int nt = 0; nt < 2; ++nt)
                    po[mt][nt] = __builtin_amdgcn_mfma_f32_16x16x32_bf16(apx[mt], bw[nt], po[mt][nt], 0, 0, 0);
        }
        float bp0 = bproj[32 * w + lo];
        float bp1 = bproj[32 * w + 16 + lo];
        float* outb = out + (size_t)b * TTOT * C_;
#pragma unroll
        for (int mt = 0; mt < 4; ++mt) {
#pragma unroll
            for (int r = 0; r < 4; ++r) {
                int row = mt * 16 + hi * 4 + r;
                int tok = (wi * 8 + (row >> 3)) * WIMG + wj * 8 + (row & 7);
                float* orow = outb + (size_t)tok * C_ + 32 * w + lo;
                orow[0]  = po[mt][0][r] + bp0;
                orow[16] = po[mt][1][r] + bp1;
            }
        }
    } else {
        // ================= token path: one block per (b,set) =================
        const int tb  = bx;
        const int b   = tb >> 1;
        const int set = tb & 1;
        const float* src = set ? (inter + (size_t)b * 100 * C_) : (det + (size_t)b * 100 * C_);
        __bf16* xs  = (__bf16*)(SMEM + TOK_XS_OFF);   // [100][136]: x, later px
        __bf16* qs  = (__bf16*)(SMEM + TOK_QS_OFF);   // [100][34]
        __bf16* ks2 = (__bf16*)(SMEM + TOK_KS_OFF);
        __bf16* vs2 = (__bf16*)(SMEM + TOK_VS_OFF);
        float* qkvT = qkvT_ws + (size_t)tb * 38400;

        for (int i = tid; i < 12800; i += 512) {
            int t = i >> 7, c = i & 127;
            xs[t * PX_STRIDE + c] = (__bf16)src[i];
        }
        __syncthreads();

        // qkv: qkvT[n*100+t] (n-major)
        for (int idx = tid; idx < 38400; idx += 512) {
            int n = idx / 100;
            int t = idx - n * 100;
            float s = 0.f;
#pragma unroll
            for (int k = 0; k < 128; k += 8) {
                bf16x8 xv = *(const bf16x8*)&xs[t * PX_STRIDE + k];
                bf16x8 wv = *(const bf16x8*)&wq[n * C_ + k];
#pragma unroll
                for (int u = 0; u < 8; ++u) s += (float)xv[u] * (float)wv[u];
            }
            qkvT[idx] = s + bqkv[n];
        }
        __syncthreads();

        for (int h = 0; h < 4; ++h) {
            for (int i = tid; i < 3200; i += 512) {
                int nl = i / 100;
                int t = i - nl * 100;
                qs[t * TOK_STR + nl]  = (__bf16)qkvT[(32 * h + nl) * 100 + t];
                ks2[t * TOK_STR + nl] = (__bf16)qkvT[(128 + 32 * h + nl) * 100 + t];
                vs2[t * TOK_STR + nl] = (__bf16)qkvT[(256 + 32 * h + nl) * 100 + t];
            }
            __syncthreads();
            if (tid < 100) {
                int t = tid;
                float qreg[32];
#pragma unroll
                for (int d = 0; d < 32; ++d) qreg[d] = (float)qs[t * TOK_STR + d];
                float m = -1e30f;
                for (int j = 0; j < 100; ++j) {
                    float s = 0.f;
#pragma unroll
                    for (int d = 0; d < 32; ++d) s += qreg[d] * (float)ks2[j * TOK_STR + d];
                    m = fmaxf(m, s * SCALE);
                }
                float sum = 0.f;
                float acc32[32];
#pragma unroll
                for (int d = 0; d < 32; ++d) acc32[d] = 0.f;
                for (int j = 0; j < 100; ++j) {
                    float s = 0.f;
#pragma unroll
                    for (int d = 0; d < 32; ++d) s += qreg[d] * (float)ks2[j * TOK_STR + d];
                    float p = __expf(s * SCALE - m);
                    sum += p;
#pragma unroll
                    for (int d = 0; d < 32; ++d) acc32[d] += p * (float)vs2[j * TOK_STR + d];
                }
                float inv = 1.0f / sum;
#pragma unroll
                for (int d = 0; d < 32; ++d)
                    xs[t * PX_STRIDE + 32 * h + d] = (__bf16)(acc32[d] * inv);
            }
            __syncthreads();
        }

        for (int idx = tid; idx < 12800; idx += 512) {
            int t = idx >> 7, c = idx & 127;
            float s = 0.f;
#pragma unroll
            for (int k = 0; k < 128; k += 8) {
                bf16x8 a = *(const bf16x8*)&xs[t * PX_STRIDE + k];
                bf16x8 bwv = *(const bf16x8*)&wp[c * C_ + k];
#pragma unroll
                for (int u = 0; u < 8; ++u) s += (float)a[u] * (float)bwv[u];
            }
            out[((size_t)b * TTOT + NPATCH + set * 100 + t) * C_ + c] = s + bproj[c];
        }
    }
}

// ---------------------------------------------------------------- launch
extern "C" void kernel_launch(void* const* d_in, const int* in_sizes, int n_in,
                              void* d_out, int out_size, void* d_ws, size_t ws_size,
                              hipStream_t stream) {
    const float* x         = (const float*)d_in[0];
    const float* det       = (const float*)d_in[1];
    const float* inter     = (const float*)d_in[2];
    const float* mask      = (const float*)d_in[3];
    const float* Wq        = (const float*)d_in[4];
    const float* bq        = (const float*)d_in[5];
    const float* Wp        = (const float*)d_in[6];
    const float* bp        = (const float*)d_in[7];
    const float* rel_table = (const float*)d_in[8];
    const int*   rel_index = (const int*)d_in[9];
    float* out = (float*)d_out;

    char* ws = (char*)d_ws;
    unsigned short* wq_b = (unsigned short*)(ws + WS_WQ);
    unsigned short* wp_b = (unsigned short*)(ws + WS_WP);
    float* biasP         = (float*)(ws + WS_BIASP);
    float* qkvT_ws       = (float*)(ws + WS_QKVTOK);

    prep_kernel<<<320, 256, 0, stream>>>(Wq, Wp, rel_table, rel_index, wq_b, wp_b, biasP);
    // 8 token blocks + 2048 window blocks (2 windows each, exact)
    win2_kernel<<<8 + 2048, 512, 0, stream>>>(x, det, inter, mask, wq_b, bq, wp_b, bp,
                                              biasP, qkvT_ws, out);
}

// Round 9
// 445.291 us; speedup vs baseline: 1.0040x; 1.0040x over previous
//
#include <hip/hip_runtime.h>

#define B_    4
#define HIMG  256
#define WIMG  256
#define C_    128
#define NH_   4
#define WS8   8
#define L_    64
#define NWX   32
#define NPATCH (HIMG*WIMG)           // 65536
#define TTOT  (NPATCH + 200)         // 65736
#define SCALE 0.17677669529663689f   // 32^-0.5

typedef __bf16 bf16x8 __attribute__((ext_vector_type(8)));
typedef __bf16 bf16x4 __attribute__((ext_vector_type(4)));
typedef float  f32x4  __attribute__((ext_vector_type(4)));

// ---- shared memory: two windows per 512-thread block, 54272 B each ----
// RULE (measured R5 vs R8/R6): workgroup LDS must stay <= 128 KiB on gfx950;
// 143360/162816 B halved effective occupancy (22.6%->12.7%).
// per-window region (offset win*54272):
//   per-wave scratch @ w*13568: [64][72] bf16 Q(cols 0..31)|K(cols 32..63), P overlays
//                               [32][68] bf16 V^T @ +9216
//   px exchange [64][136] bf16 overlays offset 0 after barrier
#define WIN_BYTES  54272
#define SMEM_BYTES (2*WIN_BYTES)     // 108544 <= 131072: full 8-wave residency
#define QK_STRIDE  72
#define KOFF       32
#define VT_OFF     9216
#define VT_STRIDE  68
#define WV_BYTES   13568
#define PX_STRIDE  136
// token-block reuse of window-0 region (47600 B used):
#define TOK_XS_OFF 0
#define TOK_QS_OFF 27200
#define TOK_KS_OFF 34000
#define TOK_VS_OFF 40800
#define TOK_STR    34

// ---- workspace layout (bytes) ----
#define WS_WQ     0          // 384*128 bf16 = 98304
#define WS_WP     98304      // 128*128 bf16 = 32768
#define WS_BIASP  131072     // 4*64*16*4 f32 = 65536  (biasP[h][row][lo][nt])
#define WS_QKVTOK 196608     // 8 * 38400 f32 = 1228800

// ---------------------------------------------------------------- prep
__global__ __launch_bounds__(256)
void prep_kernel(const float* __restrict__ Wq, const float* __restrict__ Wp,
                 const float* __restrict__ rel_table, const int* __restrict__ rel_index,
                 unsigned short* __restrict__ wq_b, unsigned short* __restrict__ wp_b,
                 float* __restrict__ biasP) {
    int id = blockIdx.x * 256 + threadIdx.x;
    if (id < 49152) {
        __bf16 v = (__bf16)Wq[id];
        wq_b[id] = *(unsigned short*)&v;
    } else if (id < 65536) {
        int i = id - 49152;
        __bf16 v = (__bf16)Wp[i];
        wp_b[i] = *(unsigned short*)&v;
    } else if (id < 81920) {
        int t = id - 65536;
        int h = t >> 12, ij = t & 4095;
        int row = ij >> 6, col = ij & 63;
        // transposed: [h][row][lo][nt] so softmax reads one float4 per (row,lo)
        biasP[((h * 64 + row) * 16 + (col & 15)) * 4 + (col >> 4)] =
            rel_table[rel_index[ij] * 4 + h];
    }
}

// ---------------------------------------------------------------- fused kernel
// blocks 0..7: token path (b,set), dispatched first -> hidden under window work.
// blocks 8..2055: 2 windows each (8 waves forced co-resident, R5 mechanism).
__global__ __launch_bounds__(512, 2)
void win2_kernel(const float* __restrict__ x, const float* __restrict__ det,
                 const float* __restrict__ inter, const float* __restrict__ mask,
                 const unsigned short* __restrict__ wq_u, const float* __restrict__ bqkv,
                 const unsigned short* __restrict__ wp_u, const float* __restrict__ bproj,
                 const float* __restrict__ biasP, float* __restrict__ qkvT_ws,
                 float* __restrict__ out) {
    __shared__ __align__(16) char SMEM[SMEM_BYTES];
    const __bf16* wq = (const __bf16*)wq_u;
    const __bf16* wp = (const __bf16*)wp_u;
    const int tid = threadIdx.x;
    const int bx = blockIdx.x;
    const f32x4 zz = {0.f, 0.f, 0.f, 0.f};

    if (bx >= 8) {
        // ================= window path =================
        const int win = tid >> 8;            // 0..1: window-in-block
        const int w   = (tid >> 6) & 3;      // wave-in-window == head
        const int l   = tid & 63;
        const int lo  = l & 15;
        const int hi  = l >> 4;

        const int gw = (bx - 8) * 2 + win;   // 0..4095 exact
        const int b  = gw >> 10;
        const int wi = (gw >> 5) & 31;
        const int wj = gw & 31;

        char* WB = SMEM + win * WIN_BYTES;
        __bf16* SW  = (__bf16*)(WB + w * WV_BYTES);            // [64][72]: Q|K, later P
        __bf16* VTs = (__bf16*)(WB + w * WV_BYTES + VT_OFF);   // [32][68]: V^T
        __bf16* PXU = (__bf16*)WB;                             // [64][136]: px union

        // ---------------- phase 1: QKV accumulators
        const float* xw = x + (((size_t)(b * HIMG) + wi * WS8) * WIMG + wj * WS8) * C_;
        const float* arow[4];
#pragma unroll
        for (int mt = 0; mt < 4; ++mt) {
            int t = mt * 16 + lo;
            arow[mt] = xw + ((size_t)(t >> 3) * WIMG + (t & 7)) * C_ + hi * 8;
        }
        int nbase[6];
        const __bf16* brow[6];
#pragma unroll
        for (int g = 0; g < 3; ++g) {
            nbase[2 * g]     = g * 128 + 32 * w;
            nbase[2 * g + 1] = g * 128 + 32 * w + 16;
        }
#pragma unroll
        for (int nt = 0; nt < 6; ++nt)
            brow[nt] = wq + (size_t)(nbase[nt] + lo) * C_ + hi * 8;

        f32x4 acc[4][6];
#pragma unroll
        for (int mt = 0; mt < 4; ++mt)
#pragma unroll
            for (int nt = 0; nt < 6; ++nt) acc[mt][nt] = zz;

#pragma unroll
        for (int ks = 0; ks < 4; ++ks) {
            bf16x8 a[4], bb[6];
#pragma unroll
            for (int mt = 0; mt < 4; ++mt) {
                const float* pa = arow[mt] + ks * 32;
                float4 v0 = *(const float4*)pa;
                float4 v1 = *(const float4*)(pa + 4);
                bf16x8 av;
                av[0] = (__bf16)v0.x; av[1] = (__bf16)v0.y; av[2] = (__bf16)v0.z; av[3] = (__bf16)v0.w;
                av[4] = (__bf16)v1.x; av[5] = (__bf16)v1.y; av[6] = (__bf16)v1.z; av[7] = (__bf16)v1.w;
                a[mt] = av;
            }
#pragma unroll
            for (int nt = 0; nt < 6; ++nt)
                bb[nt] = *(const bf16x8*)(brow[nt] + ks * 32);
#pragma unroll
            for (int mt = 0; mt < 4; ++mt)
#pragma unroll
                for (int nt = 0; nt < 6; ++nt)
                    acc[mt][nt] = __builtin_amdgcn_mfma_f32_16x16x32_bf16(a[mt], bb[nt], acc[mt][nt], 0, 0, 0);
        }

        // ---------------- scatter Q, K, V^T to LDS (write all, then read)
#pragma unroll
        for (int nt = 0; nt < 6; ++nt) {
            float bq = bqkv[nbase[nt] + lo];
            if (nt < 2) {
                int col = nt * 16 + lo;
#pragma unroll
                for (int mt = 0; mt < 4; ++mt)
#pragma unroll
                    for (int r = 0; r < 4; ++r)
                        SW[(mt * 16 + hi * 4 + r) * QK_STRIDE + col] = (__bf16)(acc[mt][nt][r] + bq);
            } else if (nt < 4) {
                int col = KOFF + (nt - 2) * 16 + lo;
#pragma unroll
                for (int mt = 0; mt < 4; ++mt)
#pragma unroll
                    for (int r = 0; r < 4; ++r)
                        SW[(mt * 16 + hi * 4 + r) * QK_STRIDE + col] = (__bf16)(acc[mt][nt][r] + bq);
            } else {
                int d = (nt - 4) * 16 + lo;
#pragma unroll
                for (int mt = 0; mt < 4; ++mt) {
                    bf16x4 vv;
#pragma unroll
                    for (int r = 0; r < 4; ++r) vv[r] = (__bf16)(acc[mt][nt][r] + bq);
                    *(bf16x4*)&VTs[d * VT_STRIDE + mt * 16 + hi * 4] = vv;
                }
            }
        }

        bf16x8 aq[4], bk[4];
#pragma unroll
        for (int mt = 0; mt < 4; ++mt)
            aq[mt] = *(const bf16x8*)&SW[(mt * 16 + lo) * QK_STRIDE + hi * 8];
#pragma unroll
        for (int nt = 0; nt < 4; ++nt)
            bk[nt] = *(const bf16x8*)&SW[(nt * 16 + lo) * QK_STRIDE + KOFF + hi * 8];

        // ---------------- QK^T
        f32x4 lg[4][4];
#pragma unroll
        for (int mt = 0; mt < 4; ++mt)
#pragma unroll
            for (int nt = 0; nt < 4; ++nt)
                lg[mt][nt] = __builtin_amdgcn_mfma_f32_16x16x32_bf16(aq[mt], bk[nt], zz, 0, 0, 0);

        // ---------------- softmax, P -> scratch (overlays Q/K; both in regs)
        // bias: 1 f32x4 per (mt,r) from transposed biasP (L2-hot 64KB table);
        // mask: scalar global (R5-proven).
        const float* maskW = mask + (size_t)(wi * NWX + wj) * 4096;
#pragma unroll
        for (int mt = 0; mt < 4; ++mt) {
#pragma unroll
            for (int r = 0; r < 4; ++r) {
                int row = mt * 16 + hi * 4 + r;
                f32x4 bv4 = *(const f32x4*)&biasP[((w * 64 + row) * 16 + lo) * 4];
                const float* mrow = maskW + row * 64 + lo;
                float v[4];
                float m = -1e30f;
#pragma unroll
                for (int nt = 0; nt < 4; ++nt) {
                    float t = lg[mt][nt][r] * SCALE + bv4[nt] + mrow[nt * 16];
                    v[nt] = t;
                    m = fmaxf(m, t);
                }
                m = fmaxf(m, __shfl_xor(m, 1));
                m = fmaxf(m, __shfl_xor(m, 2));
                m = fmaxf(m, __shfl_xor(m, 4));
                m = fmaxf(m, __shfl_xor(m, 8));
                float s = 0.f;
#pragma unroll
                for (int nt = 0; nt < 4; ++nt) { v[nt] = __expf(v[nt] - m); s += v[nt]; }
                s += __shfl_xor(s, 1);
                s += __shfl_xor(s, 2);
                s += __shfl_xor(s, 4);
                s += __shfl_xor(s, 8);
                float inv = 1.0f / s;
#pragma unroll
                for (int nt = 0; nt < 4; ++nt)
                    SW[row * QK_STRIDE + nt * 16 + lo] = (__bf16)(v[nt] * inv);
            }
        }

        // ---------------- PV
        f32x4 pv[4][2];
#pragma unroll
        for (int mt = 0; mt < 4; ++mt)
#pragma unroll
            for (int nt = 0; nt < 2; ++nt) pv[mt][nt] = zz;
#pragma unroll
        for (int ks = 0; ks < 2; ++ks) {
            bf16x8 ap[4], bv[2];
#pragma unroll
            for (int mt = 0; mt < 4; ++mt)
                ap[mt] = *(const bf16x8*)&SW[(mt * 16 + lo) * QK_STRIDE + ks * 32 + hi * 8];
#pragma unroll
            for (int nt = 0; nt < 2; ++nt) {
                bf16x4 b0 = *(const bf16x4*)&VTs[(nt * 16 + lo) * VT_STRIDE + ks * 32 + hi * 8];
                bf16x4 b1 = *(const bf16x4*)&VTs[(nt * 16 + lo) * VT_STRIDE + ks * 32 + hi * 8 + 4];
                bf16x8 bb;
#pragma unroll
                for (int u = 0; u < 4; ++u) { bb[u] = b0[u]; bb[u + 4] = b1[u]; }
                bv[nt] = bb;
            }
#pragma unroll
            for (int mt = 0; mt < 4; ++mt)
#pragma unroll
                for (int nt = 0; nt < 2; ++nt)
                    pv[mt][nt] = __builtin_amdgcn_mfma_f32_16x16x32_bf16(ap[mt], bv[nt], pv[mt][nt], 0, 0, 0);
        }

        // ---------------- px exchange through per-window scratch union
        __syncthreads();   // all waves done reading their scratch
#pragma unroll
        for (int mt = 0; mt < 4; ++mt)
#pragma unroll
            for (int nt = 0; nt < 2; ++nt)
#pragma unroll
                for (int r = 0; r < 4; ++r)
                    PXU[(mt * 16 + hi * 4 + r) * PX_STRIDE + 32 * w + nt * 16 + lo] = (__bf16)pv[mt][nt][r];
        __syncthreads();

        // ---------------- proj (wave w -> out cols [32w, 32w+32))
        f32x4 po[4][2];
#pragma unroll
        for (int mt = 0; mt < 4; ++mt)
#pragma unroll
            for (int nt = 0; nt < 2; ++nt) po[mt][nt] = zz;
        const __bf16* wprow[2];
#pragma unroll
        for (int nt = 0; nt < 2; ++nt)
            wprow[nt] = wp + (size_t)(32 * w + nt * 16 + lo) * C_ + hi * 8;
#pragma unroll
        for (int ks = 0; ks < 4; ++ks) {
            bf16x8 apx[4], bw[2];
#pragma unroll
            for (int mt = 0; mt < 4; ++mt)
                apx[mt] = *(const bf16x8*)&PXU[(mt * 16 + lo) * PX_STRIDE + ks * 32 + hi * 8];
#pragma unroll
            for (int nt = 0; nt < 2; ++nt)
                bw[nt] = *(const bf16x8*)(wprow[nt] + ks * 32);
#pragma unroll
            for (int mt = 0; mt < 4; ++mt)
#pragma unroll
                for (int nt = 0; nt < 2; ++nt)
                    po[mt][nt] = __builtin_amdgcn_mfma_f32_16x16x32_bf16(apx[mt], bw[nt], po[mt][nt], 0, 0, 0);
        }
        float bp0 = bproj[32 * w + lo];
        float bp1 = bproj[32 * w + 16 + lo];
        float* outb = out + (size_t)b * TTOT * C_;
#pragma unroll
        for (int mt = 0; mt < 4; ++mt) {
#pragma unroll
            for (int r = 0; r < 4; ++r) {
                int row = mt * 16 + hi * 4 + r;
                int tok = (wi * 8 + (row >> 3)) * WIMG + wj * 8 + (row & 7);
                float* orow = outb + (size_t)tok * C_ + 32 * w + lo;
                orow[0]  = po[mt][0][r] + bp0;
                orow[16] = po[mt][1][r] + bp1;
            }
        }
    } else {
        // ================= token path: one block per (b,set) =================
        const int tb  = bx;
        const int b   = tb >> 1;
        const int set = tb & 1;
        const float* src = set ? (inter + (size_t)b * 100 * C_) : (det + (size_t)b * 100 * C_);
        __bf16* xs  = (__bf16*)(SMEM + TOK_XS_OFF);   // [100][136]: x, later px
        __bf16* qs  = (__bf16*)(SMEM + TOK_QS_OFF);   // [100][34]
        __bf16* ks2 = (__bf16*)(SMEM + TOK_KS_OFF);
        __bf16* vs2 = (__bf16*)(SMEM + TOK_VS_OFF);
        float* qkvT = qkvT_ws + (size_t)tb * 38400;

        for (int i = tid; i < 12800; i += 512) {
            int t = i >> 7, c = i & 127;
            xs[t * PX_STRIDE + c] = (__bf16)src[i];
        }
        __syncthreads();

        // qkv: qkvT[n*100+t] (n-major)
        for (int idx = tid; idx < 38400; idx += 512) {
            int n = idx / 100;
            int t = idx - n * 100;
            float s = 0.f;
#pragma unroll
            for (int k = 0; k < 128; k += 8) {
                bf16x8 xv = *(const bf16x8*)&xs[t * PX_STRIDE + k];
                bf16x8 wv = *(const bf16x8*)&wq[n * C_ + k];
#pragma unroll
                for (int u = 0; u < 8; ++u) s += (float)xv[u] * (float)wv[u];
            }
            qkvT[idx] = s + bqkv[n];
        }
        __syncthreads();

        for (int h = 0; h < 4; ++h) {
            for (int i = tid; i < 3200; i += 512) {
                int nl = i / 100;
                int t = i - nl * 100;
                qs[t * TOK_STR + nl]  = (__bf16)qkvT[(32 * h + nl) * 100 + t];
                ks2[t * TOK_STR + nl] = (__bf16)qkvT[(128 + 32 * h + nl) * 100 + t];
                vs2[t * TOK_STR + nl] = (__bf16)qkvT[(256 + 32 * h + nl) * 100 + t];
            }
            __syncthreads();
            if (tid < 100) {
                int t = tid;
                float qreg[32];
#pragma unroll
                for (int d = 0; d < 32; ++d) qreg[d] = (float)qs[t * TOK_STR + d];
                float m = -1e30f;
                for (int j = 0; j < 100; ++j) {
                    float s = 0.f;
#pragma unroll
                    for (int d = 0; d < 32; ++d) s += qreg[d] * (float)ks2[j * TOK_STR + d];
                    m = fmaxf(m, s * SCALE);
                }
                float sum = 0.f;
                float acc32[32];
#pragma unroll
                for (int d = 0; d < 32; ++d) acc32[d] = 0.f;
                for (int j = 0; j < 100; ++j) {
                    float s = 0.f;
#pragma unroll
                    for (int d = 0; d < 32; ++d) s += qreg[d] * (float)ks2[j * TOK_STR + d];
                    float p = __expf(s * SCALE - m);
                    sum += p;
#pragma unroll
                    for (int d = 0; d < 32; ++d) acc32[d] += p * (float)vs2[j * TOK_STR + d];
                }
                float inv = 1.0f / sum;
#pragma unroll
                for (int d = 0; d < 32; ++d)
                    xs[t * PX_STRIDE + 32 * h + d] = (__bf16)(acc32[d] * inv);
            }
            __syncthreads();
        }

        for (int idx = tid; idx < 12800; idx += 512) {
            int t = idx >> 7, c = idx & 127;
            float s = 0.f;
#pragma unroll
            for (int k = 0; k < 128; k += 8) {
                bf16x8 a = *(const bf16x8*)&xs[t * PX_STRIDE + k];
                bf16x8 bwv = *(const bf16x8*)&wp[c * C_ + k];
#pragma unroll
                for (int u = 0; u < 8; ++u) s += (float)a[u] * (float)bwv[u];
            }
            out[((size_t)b * TTOT + NPATCH + set * 100 + t) * C_ + c] = s + bproj[c];
        }
    }
}

// ---------------------------------------------------------------- launch
extern "C" void kernel_launch(void* const* d_in, const int* in_sizes, int n_in,
                              void* d_out, int out_size, void* d_ws, size_t ws_size,
                              hipStream_t stream) {
    const float* x         = (const float*)d_in[0];
    const float* det       = (const float*)d_in[1];
    const float* inter     = (const float*)d_in[2];
    const float* mask      = (const float*)d_in[3];
    const float* Wq        = (const float*)d_in[4];
    const float* bq        = (const float*)d_in[5];
    const float* Wp        = (const float*)d_in[6];
    const float* bp        = (const float*)d_in[7];
    const float* rel_table = (const float*)d_in[8];
    const int*   rel_index = (const int*)d_in[9];
    float* out = (float*)d_out;

    char* ws = (char*)d_ws;
    unsigned short* wq_b = (unsigned short*)(ws + WS_WQ);
    unsigned short* wp_b = (unsigned short*)(ws + WS_WP);
    float* biasP         = (float*)(ws + WS_BIASP);
    float* qkvT_ws       = (float*)(ws + WS_QKVTOK);

    prep_kernel<<<320, 256, 0, stream>>>(Wq, Wp, rel_table, rel_index, wq_b, wp_b, biasP);
    // 8 token blocks + 2048 window blocks (2 windows each, exact)
    win2_kernel<<<8 + 2048, 512, 0, stream>>>(x, det, inter, mask, wq_b, bq, wp_b, bp,
                                              biasP, qkvT_ws, out);
}

// Round 10
// 290.252 us; speedup vs baseline: 1.5402x; 1.5342x over previous
//
#include <hip/hip_runtime.h>

#define B_    4
#define HIMG  256
#define WIMG  256
#define C_    128
#define NH_   4
#define WS8   8
#define L_    64
#define NWX   32
#define NPATCH (HIMG*WIMG)           // 65536
#define TTOT  (NPATCH + 200)         // 65736
#define SCALE 0.17677669529663689f   // 32^-0.5

typedef __bf16 bf16x8 __attribute__((ext_vector_type(8)));
typedef __bf16 bf16x4 __attribute__((ext_vector_type(4)));
typedef float  f32x4  __attribute__((ext_vector_type(4)));

// ---- shared memory: two windows per 512-thread block, 54272 B each (R5) ----
// per-window region (offset win*54272):
//   per-wave scratch @ w*13568: [64][72] bf16 Q(cols 0..31)|K(cols 32..63), P overlays
//                               [32][68] bf16 V^T @ +9216
//   px exchange [64][136] bf16 overlays offset 0 after barrier
#define WIN_BYTES  54272
#define SMEM_BYTES (2*WIN_BYTES)     // 108544
#define QK_STRIDE  72
#define KOFF       32
#define VT_OFF     9216
#define VT_STRIDE  68
#define WV_BYTES   13568
#define PX_STRIDE  136

// ---- workspace layout (bytes) ----
#define WS_WQ     0          // 384*128 bf16 = 98304
#define WS_WP     98304      // 128*128 bf16 = 32768
#define WS_BIASP  131072     // 4*64*16*4 f32 = 65536  (biasP[h][row][lo][nt])
#define WS_QKVTOK 196608     // 800*384 f32 = 1228800
#define WS_PXTOK  1425408    // 800*128 f32 = 409600
#define WS_MASKP  1835008    // 1024*64*16*4 f32 = 16777216 (maskP[wij][row][lo][nt])
#define WS_NEED_MASKP (WS_MASKP + 16777216)

// ---------------------------------------------------------------- prep
// grid: 320 blocks base work; + 16384 blocks mask transpose when enabled.
__global__ __launch_bounds__(256)
void prep_kernel(const float* __restrict__ Wq, const float* __restrict__ Wp,
                 const float* __restrict__ rel_table, const int* __restrict__ rel_index,
                 const float* __restrict__ mask,
                 unsigned short* __restrict__ wq_b, unsigned short* __restrict__ wp_b,
                 float* __restrict__ biasP, float* __restrict__ maskP) {
    int id = blockIdx.x * 256 + threadIdx.x;
    if (id < 49152) {
        __bf16 v = (__bf16)Wq[id];
        wq_b[id] = *(unsigned short*)&v;
    } else if (id < 65536) {
        int i = id - 49152;
        __bf16 v = (__bf16)Wp[i];
        wp_b[i] = *(unsigned short*)&v;
    } else if (id < 81920) {
        int t = id - 65536;
        int h = t >> 12, ij = t & 4095;
        int row = ij >> 6, col = ij & 63;
        // transposed: [h][row][lo][nt] -> softmax reads one f32x4 per (row,lo)
        biasP[((h * 64 + row) * 16 + (col & 15)) * 4 + (col >> 4)] =
            rel_table[rel_index[ij] * 4 + h];
    } else if (id < 81920 + 4194304) {
        int t = id - 81920;                  // linear over mask (coalesced read)
        int wij = t >> 12, ij = t & 4095;
        int row = ij >> 6, col = ij & 63;
        maskP[((size_t)wij * 64 + row) * 64 + (col & 15) * 4 + (col >> 4)] = mask[t];
    }
}

// ---------------------------------------------------------------- window kernel
// R5 structure: 512 threads = 8 waves = 2 windows x 4 heads, forced co-residency.
// USE_MASKP: softmax mask as f32x4 from transposed table (else R5 scalar loads).
template <int USE_MASKP>
__global__ __launch_bounds__(512, 2)
void win2_kernel(const float* __restrict__ x, const float* __restrict__ mask,
                 const unsigned short* __restrict__ wq_u, const float* __restrict__ bqkv,
                 const unsigned short* __restrict__ wp_u, const float* __restrict__ bproj,
                 const float* __restrict__ biasP, const float* __restrict__ maskP,
                 float* __restrict__ out) {
    __shared__ __align__(16) char SMEM[SMEM_BYTES];
    const __bf16* wq = (const __bf16*)wq_u;
    const __bf16* wp = (const __bf16*)wp_u;
    const int tid = threadIdx.x;
    const f32x4 zz = {0.f, 0.f, 0.f, 0.f};

    const int win = tid >> 8;            // window-in-block
    const int w   = (tid >> 6) & 3;      // wave-in-window == head
    const int l   = tid & 63;
    const int lo  = l & 15;
    const int hi  = l >> 4;

    const int gw = blockIdx.x * 2 + win; // 0..4095
    const int b  = gw >> 10;
    const int wi = (gw >> 5) & 31;
    const int wj = gw & 31;

    char* WB = SMEM + win * WIN_BYTES;
    __bf16* SW  = (__bf16*)(WB + w * WV_BYTES);            // [64][72]: Q|K, later P
    __bf16* VTs = (__bf16*)(WB + w * WV_BYTES + VT_OFF);   // [32][68]: V^T
    __bf16* PXU = (__bf16*)WB;                             // [64][136]: px union

    // ---------------- phase 1: QKV accumulators
    const float* xw = x + (((size_t)(b * HIMG) + wi * WS8) * WIMG + wj * WS8) * C_;
    const float* arow[4];
#pragma unroll
    for (int mt = 0; mt < 4; ++mt) {
        int t = mt * 16 + lo;
        arow[mt] = xw + ((size_t)(t >> 3) * WIMG + (t & 7)) * C_ + hi * 8;
    }
    int nbase[6];
    const __bf16* brow[6];
#pragma unroll
    for (int g = 0; g < 3; ++g) {
        nbase[2 * g]     = g * 128 + 32 * w;
        nbase[2 * g + 1] = g * 128 + 32 * w + 16;
    }
#pragma unroll
    for (int nt = 0; nt < 6; ++nt)
        brow[nt] = wq + (size_t)(nbase[nt] + lo) * C_ + hi * 8;

    f32x4 acc[4][6];
#pragma unroll
    for (int mt = 0; mt < 4; ++mt)
#pragma unroll
        for (int nt = 0; nt < 6; ++nt) acc[mt][nt] = zz;

#pragma unroll
    for (int ks = 0; ks < 4; ++ks) {
        bf16x8 a[4], bb[6];
#pragma unroll
        for (int mt = 0; mt < 4; ++mt) {
            const float* pa = arow[mt] + ks * 32;
            float4 v0 = *(const float4*)pa;
            float4 v1 = *(const float4*)(pa + 4);
            bf16x8 av;
            av[0] = (__bf16)v0.x; av[1] = (__bf16)v0.y; av[2] = (__bf16)v0.z; av[3] = (__bf16)v0.w;
            av[4] = (__bf16)v1.x; av[5] = (__bf16)v1.y; av[6] = (__bf16)v1.z; av[7] = (__bf16)v1.w;
            a[mt] = av;
        }
#pragma unroll
        for (int nt = 0; nt < 6; ++nt)
            bb[nt] = *(const bf16x8*)(brow[nt] + ks * 32);
#pragma unroll
        for (int mt = 0; mt < 4; ++mt)
#pragma unroll
            for (int nt = 0; nt < 6; ++nt)
                acc[mt][nt] = __builtin_amdgcn_mfma_f32_16x16x32_bf16(a[mt], bb[nt], acc[mt][nt], 0, 0, 0);
    }

    // ---------------- scatter Q, K, V^T to LDS (write all, then read)
#pragma unroll
    for (int nt = 0; nt < 6; ++nt) {
        float bq = bqkv[nbase[nt] + lo];
        if (nt < 2) {
            int col = nt * 16 + lo;
#pragma unroll
            for (int mt = 0; mt < 4; ++mt)
#pragma unroll
                for (int r = 0; r < 4; ++r)
                    SW[(mt * 16 + hi * 4 + r) * QK_STRIDE + col] = (__bf16)(acc[mt][nt][r] + bq);
        } else if (nt < 4) {
            int col = KOFF + (nt - 2) * 16 + lo;
#pragma unroll
            for (int mt = 0; mt < 4; ++mt)
#pragma unroll
                for (int r = 0; r < 4; ++r)
                    SW[(mt * 16 + hi * 4 + r) * QK_STRIDE + col] = (__bf16)(acc[mt][nt][r] + bq);
        } else {
            int d = (nt - 4) * 16 + lo;
#pragma unroll
            for (int mt = 0; mt < 4; ++mt) {
                bf16x4 vv;
#pragma unroll
                for (int r = 0; r < 4; ++r) vv[r] = (__bf16)(acc[mt][nt][r] + bq);
                *(bf16x4*)&VTs[d * VT_STRIDE + mt * 16 + hi * 4] = vv;
            }
        }
    }

    bf16x8 aq[4], bk[4];
#pragma unroll
    for (int mt = 0; mt < 4; ++mt)
        aq[mt] = *(const bf16x8*)&SW[(mt * 16 + lo) * QK_STRIDE + hi * 8];
#pragma unroll
    for (int nt = 0; nt < 4; ++nt)
        bk[nt] = *(const bf16x8*)&SW[(nt * 16 + lo) * QK_STRIDE + KOFF + hi * 8];

    // ---------------- QK^T
    f32x4 lg[4][4];
#pragma unroll
    for (int mt = 0; mt < 4; ++mt)
#pragma unroll
        for (int nt = 0; nt < 4; ++nt)
            lg[mt][nt] = __builtin_amdgcn_mfma_f32_16x16x32_bf16(aq[mt], bk[nt], zz, 0, 0, 0);

    // ---------------- softmax, P -> scratch (overlays Q/K; both in regs)
    // vectorized tables: bias f32x4 always; mask f32x4 when USE_MASKP.
    const float* maskW  = mask  + (size_t)(wi * NWX + wj) * 4096;
    const float* maskPW = maskP + (size_t)(wi * NWX + wj) * 4096;
#pragma unroll
    for (int mt = 0; mt < 4; ++mt) {
#pragma unroll
        for (int r = 0; r < 4; ++r) {
            int row = mt * 16 + hi * 4 + r;
            f32x4 bv4 = *(const f32x4*)&biasP[((w * 64 + row) * 16 + lo) * 4];
            f32x4 mv4;
            if (USE_MASKP) {
                mv4 = *(const f32x4*)&maskPW[row * 64 + lo * 4];
            } else {
                const float* mrow = maskW + row * 64 + lo;
                mv4[0] = mrow[0]; mv4[1] = mrow[16]; mv4[2] = mrow[32]; mv4[3] = mrow[48];
            }
            float v[4];
            float m = -1e30f;
#pragma unroll
            for (int nt = 0; nt < 4; ++nt) {
                float t = lg[mt][nt][r] * SCALE + bv4[nt] + mv4[nt];
                v[nt] = t;
                m = fmaxf(m, t);
            }
            m = fmaxf(m, __shfl_xor(m, 1));
            m = fmaxf(m, __shfl_xor(m, 2));
            m = fmaxf(m, __shfl_xor(m, 4));
            m = fmaxf(m, __shfl_xor(m, 8));
            float s = 0.f;
#pragma unroll
            for (int nt = 0; nt < 4; ++nt) { v[nt] = __expf(v[nt] - m); s += v[nt]; }
            s += __shfl_xor(s, 1);
            s += __shfl_xor(s, 2);
            s += __shfl_xor(s, 4);
            s += __shfl_xor(s, 8);
            float inv = 1.0f / s;
#pragma unroll
            for (int nt = 0; nt < 4; ++nt)
                SW[row * QK_STRIDE + nt * 16 + lo] = (__bf16)(v[nt] * inv);
        }
    }

    // ---------------- PV
    f32x4 pv[4][2];
#pragma unroll
    for (int mt = 0; mt < 4; ++mt)
#pragma unroll
        for (int nt = 0; nt < 2; ++nt) pv[mt][nt] = zz;
#pragma unroll
    for (int ks = 0; ks < 2; ++ks) {
        bf16x8 ap[4], bv[2];
#pragma unroll
        for (int mt = 0; mt < 4; ++mt)
            ap[mt] = *(const bf16x8*)&SW[(mt * 16 + lo) * QK_STRIDE + ks * 32 + hi * 8];
#pragma unroll
        for (int nt = 0; nt < 2; ++nt) {
            bf16x4 b0 = *(const bf16x4*)&VTs[(nt * 16 + lo) * VT_STRIDE + ks * 32 + hi * 8];
            bf16x4 b1 = *(const bf16x4*)&VTs[(nt * 16 + lo) * VT_STRIDE + ks * 32 + hi * 8 + 4];
            bf16x8 bb;
#pragma unroll
            for (int u = 0; u < 4; ++u) { bb[u] = b0[u]; bb[u + 4] = b1[u]; }
            bv[nt] = bb;
        }
#pragma unroll
        for (int mt = 0; mt < 4; ++mt)
#pragma unroll
            for (int nt = 0; nt < 2; ++nt)
                pv[mt][nt] = __builtin_amdgcn_mfma_f32_16x16x32_bf16(ap[mt], bv[nt], pv[mt][nt], 0, 0, 0);
    }

    // ---------------- px exchange through per-window scratch union
    __syncthreads();   // all waves done reading their scratch
#pragma unroll
    for (int mt = 0; mt < 4; ++mt)
#pragma unroll
        for (int nt = 0; nt < 2; ++nt)
#pragma unroll
            for (int r = 0; r < 4; ++r)
                PXU[(mt * 16 + hi * 4 + r) * PX_STRIDE + 32 * w + nt * 16 + lo] = (__bf16)pv[mt][nt][r];
    __syncthreads();

    // ---------------- proj (wave w -> out cols [32w, 32w+32))
    f32x4 po[4][2];
#pragma unroll
    for (int mt = 0; mt < 4; ++mt)
#pragma unroll
        for (int nt = 0; nt < 2; ++nt) po[mt][nt] = zz;
    const __bf16* wprow[2];
#pragma unroll
    for (int nt = 0; nt < 2; ++nt)
        wprow[nt] = wp + (size_t)(32 * w + nt * 16 + lo) * C_ + hi * 8;
#pragma unroll
    for (int ks = 0; ks < 4; ++ks) {
        bf16x8 apx[4], bw[2];
#pragma unroll
        for (int mt = 0; mt < 4; ++mt)
            apx[mt] = *(const bf16x8*)&PXU[(mt * 16 + lo) * PX_STRIDE + ks * 32 + hi * 8];
#pragma unroll
        for (int nt = 0; nt < 2; ++nt)
            bw[nt] = *(const bf16x8*)(wprow[nt] + ks * 32);
#pragma unroll
        for (int mt = 0; mt < 4; ++mt)
#pragma unroll
            for (int nt = 0; nt < 2; ++nt)
                po[mt][nt] = __builtin_amdgcn_mfma_f32_16x16x32_bf16(apx[mt], bw[nt], po[mt][nt], 0, 0, 0);
    }
    float bp0 = bproj[32 * w + lo];
    float bp1 = bproj[32 * w + 16 + lo];
    float* outb = out + (size_t)b * TTOT * C_;
#pragma unroll
    for (int mt = 0; mt < 4; ++mt) {
#pragma unroll
        for (int r = 0; r < 4; ++r) {
            int row = mt * 16 + hi * 4 + r;
            int tok = (wi * 8 + (row >> 3)) * WIMG + wj * 8 + (row & 7);
            float* orow = outb + (size_t)tok * C_ + 32 * w + lo;
            orow[0]  = po[mt][0][r] + bp0;
            orow[16] = po[mt][1][r] + bp1;
        }
    }
}

// ---------------------------------------------------------------- token path (det/inter) — R5 exact
__global__ __launch_bounds__(256)
void tok_qkv_kernel(const float* __restrict__ det, const float* __restrict__ inter,
                    const float* __restrict__ Wq, const float* __restrict__ bq,
                    float* __restrict__ qkv_tok) {
    __shared__ float xs[128];
    int rid = blockIdx.x;                // 0..799
    int b = rid / 200, rem = rid % 200;
    const float* src = (rem < 100) ? det + (size_t)(b * 100 + rem) * 128
                                   : inter + (size_t)(b * 100 + rem - 100) * 128;
    int tid = threadIdx.x;
    if (tid < 128) xs[tid] = src[tid];
    __syncthreads();
    for (int n = tid; n < 384; n += 256) {
        const float* wr = Wq + (size_t)n * 128;
        float s = 0.f;
#pragma unroll 8
        for (int k = 0; k < 128; ++k) s += xs[k] * wr[k];
        qkv_tok[(size_t)rid * 384 + n] = s + bq[n];
    }
}

__global__ __launch_bounds__(256)
void tok_attn_kernel(const float* __restrict__ qkv_tok, float* __restrict__ px_tok) {
    __shared__ float qs[100 * 32];
    __shared__ float ks2[100 * 32];
    __shared__ float vs2[100 * 32];
    __shared__ float lg2[100 * 101];
    int bid = blockIdx.x;        // bs*4 + h
    int h  = bid & 3;
    int bs = bid >> 2;           // 0..7
    int rid0 = bs * 100;
    int tid = threadIdx.x;
    for (int i = tid; i < 3200; i += 256) {
        int t = i >> 5, d = i & 31;
        const float* base = qkv_tok + (size_t)(rid0 + t) * 384 + 32 * h + d;
        qs[i]  = base[0];
        ks2[i] = base[128];
        vs2[i] = base[256];
    }
    __syncthreads();
    for (int idx = tid; idx < 10000; idx += 256) {
        int i = idx / 100, j = idx % 100;
        float s = 0.f;
#pragma unroll
        for (int d = 0; d < 32; ++d) s += qs[i * 32 + d] * ks2[j * 32 + d];
        lg2[i * 101 + j] = s * SCALE;
    }
    __syncthreads();
    if (tid < 100) {
        float m = -1e30f;
        for (int j = 0; j < 100; ++j) m = fmaxf(m, lg2[tid * 101 + j]);
        float s = 0.f;
        for (int j = 0; j < 100; ++j) {
            float e = __expf(lg2[tid * 101 + j] - m);
            lg2[tid * 101 + j] = e;
            s += e;
        }
        float inv = 1.0f / s;
        for (int j = 0; j < 100; ++j) lg2[tid * 101 + j] *= inv;
    }
    __syncthreads();
    for (int idx = tid; idx < 3200; idx += 256) {
        int i = idx >> 5, d = idx & 31;
        float s = 0.f;
        for (int j = 0; j < 100; ++j) s += lg2[i * 101 + j] * vs2[j * 32 + d];
        px_tok[(size_t)(rid0 + i) * 128 + 32 * h + d] = s;
    }
}

__global__ __launch_bounds__(256)
void tok_proj_kernel(const float* __restrict__ px_tok, const float* __restrict__ Wp,
                     const float* __restrict__ bp, float* __restrict__ out) {
    int gid = blockIdx.x * 256 + threadIdx.x;   // 0..102399
    int row = gid >> 7, c = gid & 127;
    int b = row / 200, rem = row % 200;
    const float* pr = px_tok + (size_t)row * 128;
    const float* wr = Wp + (size_t)c * 128;
    float s = 0.f;
#pragma unroll 8
    for (int k = 0; k < 128; ++k) s += pr[k] * wr[k];
    out[((size_t)b * TTOT + NPATCH + rem) * 128 + c] = s + bp[c];
}

// ---------------------------------------------------------------- launch
extern "C" void kernel_launch(void* const* d_in, const int* in_sizes, int n_in,
                              void* d_out, int out_size, void* d_ws, size_t ws_size,
                              hipStream_t stream) {
    const float* x         = (const float*)d_in[0];
    const float* det       = (const float*)d_in[1];
    const float* inter     = (const float*)d_in[2];
    const float* mask      = (const float*)d_in[3];
    const float* Wq        = (const float*)d_in[4];
    const float* bq        = (const float*)d_in[5];
    const float* Wp        = (const float*)d_in[6];
    const float* bp        = (const float*)d_in[7];
    const float* rel_table = (const float*)d_in[8];
    const int*   rel_index = (const int*)d_in[9];
    float* out = (float*)d_out;

    char* ws = (char*)d_ws;
    unsigned short* wq_b = (unsigned short*)(ws + WS_WQ);
    unsigned short* wp_b = (unsigned short*)(ws + WS_WP);
    float* biasP         = (float*)(ws + WS_BIASP);
    float* qkv_tok       = (float*)(ws + WS_QKVTOK);
    float* px_tok        = (float*)(ws + WS_PXTOK);
    float* maskP         = (float*)(ws + WS_MASKP);

    const bool use_maskp = (ws_size >= (size_t)WS_NEED_MASKP);

    // prep: 320 blocks base; +16384 blocks for mask transpose when enabled
    int prep_blocks = use_maskp ? (320 + 16384) : 320;
    prep_kernel<<<prep_blocks, 256, 0, stream>>>(Wq, Wp, rel_table, rel_index, mask,
                                                 wq_b, wp_b, biasP, maskP);
    tok_qkv_kernel<<<800, 256, 0, stream>>>(det, inter, Wq, bq, qkv_tok);
    tok_attn_kernel<<<32, 256, 0, stream>>>(qkv_tok, px_tok);
    tok_proj_kernel<<<400, 256, 0, stream>>>(px_tok, Wp, bp, out);
    if (use_maskp)
        win2_kernel<1><<<2048, 512, 0, stream>>>(x, mask, wq_b, bq, wp_b, bp,
                                                 biasP, maskP, out);
    else
        win2_kernel<0><<<2048, 512, 0, stream>>>(x, mask, wq_b, bq, wp_b, bp,
                                                 biasP, maskP, out);
}